// Round 8
// baseline (80.892 us; speedup 1.0000x reference)
//
#include <hip/hip_runtime.h>
#include <hip/hip_bf16.h>
#include <math.h>

#define S_LEN   4096
#define HID     2048
#define NB      8
#define SC      128           // s-chunks: one block per 32 rows
#define S_PER   (S_LEN / SC)  // 32 rows per block
#define R       16            // TOTAL_RANK
#define AD      32            // ADAPT_DIM

typedef float f4 __attribute__((ext_vector_type(4)));

// ---------------- Kernel 1: pool + W1 projection + last-block controller ---
// grid (128 sc, 8 b), block 256. Stream/projection identical to the proven
// 56.8us version. After xpart write, each block increments cnt[b]; the LAST
// block of a batch reduces xpart[b] (16KB, L2-hot, coalesced f4) and runs
// LN + exact GELU + W2 + top-8 -> publishes ms[b][16] = rsc*mask/32.
__global__ void pool_proj(const float* __restrict__ hs,
                          const float* __restrict__ W1,
                          const float* __restrict__ b1,
                          const float* __restrict__ gamma,
                          const float* __restrict__ beta,
                          const float* __restrict__ W2,
                          const float* __restrict__ b2v,
                          const float* __restrict__ mlog,
                          const float* __restrict__ rsc,
                          float* __restrict__ xpart,
                          float* __restrict__ msout,
                          int* __restrict__ cnt) {
    __shared__ float hsum[HID];        // 8 KB (reused as f4 red[32][8] later)
    __shared__ float cpart[8][AD];     // 1 KB
    __shared__ float xv[AD];
    __shared__ float xg[AD];
    __shared__ float comb[R];
    __shared__ int   iswin;
    int t  = threadIdx.x;              // 0..255
    int sc = blockIdx.x;               // 0..127
    int b  = blockIdx.y;               // 0..7

    const float* base = hs + ((size_t)b * S_LEN + (size_t)sc * S_PER) * HID;
    const f4* p0 = (const f4*)(base + t * 4);          // cols [t*4 .. t*4+3]
    const f4* p1 = (const f4*)(base + 1024 + t * 4);   // cols [1024+t*4 ..]
    f4 a0 = (f4)(0.f);
    f4 a1 = (f4)(0.f);
#pragma unroll 8
    for (int s = 0; s < S_PER; ++s) {
        f4 v0 = __builtin_nontemporal_load(p0 + (size_t)s * (HID / 4));
        f4 v1 = __builtin_nontemporal_load(p1 + (size_t)s * (HID / 4));
        a0 += v0;
        a1 += v1;
    }
    *(f4*)&hsum[t * 4]        = a0;
    *(f4*)&hsum[1024 + t * 4] = a1;
    __syncthreads();

    // c[j] = sum_h hsum[h]*W1[h][j]; 8 groups of 32 lanes, W1 L2-resident
    int j = t & 31, g = t >> 5;
    const float* w = W1 + (size_t)(g * 256) * AD + j;
    float c = 0.f;
#pragma unroll 4
    for (int k = 0; k < 256; ++k)
        c += hsum[g * 256 + k] * w[(size_t)k * AD];
    cpart[g][j] = c;
    __syncthreads();

    if (t < AD) {
        float s = 0.f;
#pragma unroll
        for (int gg = 0; gg < 8; ++gg) s += cpart[gg][t];
        xpart[((size_t)(b * SC + sc)) * AD + t] = s;
    }

    // ---- last-block-per-batch controller ----
    if (t == 0) {
        __threadfence();                         // release xpart (L2 wb)
        int old = atomicAdd(&cnt[b], 1);
        iswin = (old == SC - 1);
        if (iswin) __threadfence();              // acquire others' xpart
    }
    __syncthreads();
    if (!iswin) return;

    // coalesced reduce of xpart[b][128][32]: lane owns 4 cols, 32 row-phases
    {
        f4* red = (f4*)hsum;                     // reuse LDS: [32][8] f4
        const f4* xp4 = (const f4*)(xpart + (size_t)b * SC * AD);
        int c4 = t & 7, rg = t >> 3;             // 0..7, 0..31
        f4 acc = (f4)(0.f);
#pragma unroll
        for (int r = 0; r < 4; ++r)
            acc += xp4[(size_t)(rg + r * 32) * 8 + c4];
        red[rg * 8 + c4] = acc;
    }
    __syncthreads();
    if (t < 8) {
        f4* red = (f4*)hsum;
        f4 s = (f4)(0.f);
#pragma unroll
        for (int rg = 0; rg < 32; ++rg) s += red[rg * 8 + t];
        xv[t * 4 + 0] = s.x * (1.0f / (float)S_LEN) + b1[t * 4 + 0];
        xv[t * 4 + 1] = s.y * (1.0f / (float)S_LEN) + b1[t * 4 + 1];
        xv[t * 4 + 2] = s.z * (1.0f / (float)S_LEN) + b1[t * 4 + 2];
        xv[t * 4 + 3] = s.w * (1.0f / (float)S_LEN) + b1[t * 4 + 3];
    }
    __syncthreads();

    if (t < AD) {
        float mu = 0.f;
#pragma unroll
        for (int k = 0; k < AD; ++k) mu += xv[k];
        mu *= (1.0f / AD);
        float var = 0.f;
#pragma unroll
        for (int k = 0; k < AD; ++k) { float d = xv[k] - mu; var += d * d; }
        var *= (1.0f / AD);
        float x = (xv[t] - mu) * rsqrtf(var + 1e-5f) * gamma[t] + beta[t];
        xg[t] = 0.5f * x * (1.0f + erff(x * 0.70710678118654752f)); // exact GELU
    }
    __syncthreads();

    if (t < R) {
        float lg = b2v[t];
#pragma unroll
        for (int k = 0; k < AD; ++k) lg += xg[k] * W2[(size_t)k * R + t];
        comb[t] = lg + mlog[t];
    }
    __syncthreads();

    if (t < R) {
        float v = comb[t];
        int cn = 0;
#pragma unroll
        for (int k = 0; k < R; ++k)
            cn += (comb[k] > v) || (comb[k] == v && k < t);
        msout[b * R + t] = (cn < 8) ? rsc[t] * 0.03125f : 0.f;  // fold 1/32
    }
}

// ---------------- Kernel 2: pure stream — masked FWHT-16 ----------------
// 128 blocks x 256 threads, one 16-float row per thread (256 rows/block,
// 16 blocks per batch). Mask is 16 precomputed floats per batch.
__global__ void apply_hadamard(const float* __restrict__ msout,
                               const float* __restrict__ ra,
                               float* __restrict__ out) {
    __shared__ float ms[R];
    int t   = threadIdx.x;            // 0..255
    int blk = blockIdx.x;             // 0..127
    int b   = blk >> 4;               // 16 blocks per batch
    if (t < R) ms[t] = msout[b * R + t];
    __syncthreads();

    size_t row = (size_t)blk * 256 + t;
    const f4* src = (const f4*)(ra + row * R);
    float a[R];
#pragma unroll
    for (int i = 0; i < 4; ++i) {
        f4 v = __builtin_nontemporal_load(src + i);
        a[4 * i + 0] = v.x; a[4 * i + 1] = v.y;
        a[4 * i + 2] = v.z; a[4 * i + 3] = v.w;
    }
#pragma unroll
    for (int r = 0; r < R; ++r) a[r] *= ms[r];

    // FWHT-16 (Sylvester); 1/32 already folded into ms
#pragma unroll
    for (int hstep = 1; hstep < R; hstep <<= 1) {
#pragma unroll
        for (int i = 0; i < R; ++i) {
            if ((i & hstep) == 0) {
                float u = a[i], v = a[i | hstep];
                a[i] = u + v; a[i | hstep] = u - v;
            }
        }
    }

    f4* dst = (f4*)(out + row * R);
#pragma unroll
    for (int i = 0; i < 4; ++i) {
        f4 v;
        v.x = a[4 * i + 0]; v.y = a[4 * i + 1];
        v.z = a[4 * i + 2]; v.w = a[4 * i + 3];
        __builtin_nontemporal_store(v, dst + i);
    }
}

extern "C" void kernel_launch(void* const* d_in, const int* in_sizes, int n_in,
                              void* d_out, int out_size, void* d_ws, size_t ws_size,
                              hipStream_t stream) {
    const float* hs    = (const float*)d_in[0];  // (8,4096,2048)
    const float* ra    = (const float*)d_in[1];  // (8,4096,16)
    const float* W1    = (const float*)d_in[2];  // (2048,32)
    const float* b1    = (const float*)d_in[3];  // (32)
    const float* gamma = (const float*)d_in[4];  // (32)
    const float* beta  = (const float*)d_in[5];  // (32)
    const float* W2    = (const float*)d_in[6];  // (32,16)
    const float* b2v   = (const float*)d_in[7];  // (16)
    const float* mlog  = (const float*)d_in[8];  // (16)
    const float* rsc   = (const float*)d_in[9];  // (16)
    float* out = (float*)d_out;

    float* xpart = (float*)d_ws;                     // 1024*32 f32 = 128 KB
    float* msout = xpart + (size_t)NB * SC * AD;     // 128 f32
    int*   cnt   = (int*)(msout + NB * R);           // 8 ints

    hipMemsetAsync(cnt, 0, NB * sizeof(int), stream);
    pool_proj     <<<dim3(SC, NB), 256, 0, stream>>>(hs, W1, b1, gamma, beta,
                                                     W2, b2v, mlog, rsc,
                                                     xpart, msout, cnt);
    apply_hadamard<<<128, 256, 0, stream>>>(msout, ra, out);
}

// Round 9
// 54.465 us; speedup vs baseline: 1.4852x; 1.4852x over previous
//
#include <hip/hip_runtime.h>
#include <hip/hip_bf16.h>
#include <math.h>

#define S_LEN   4096
#define HID     2048
#define NB      8
#define SC      64            // s-chunks: one block per 64 rows
#define S_PER   (S_LEN / SC)  // 64 rows per block
#define R       16            // TOTAL_RANK
#define AD      32            // ADAPT_DIM

typedef float f4 __attribute__((ext_vector_type(4)));

// ---------------- Kernel 1: fused mean-pool + W1 projection ----------------
// grid (64 sc, 8 b) = 512 blocks x 512 threads (2 blocks/CU, 16 waves/CU —
// same latency hiding as R3's 4x4). One f4 column-stream per thread (64 NT
// loads); projection loop halved to 128 iters; W1 L2 traffic halved.
__global__ __launch_bounds__(512)
void pool_proj(const float* __restrict__ hs,
               const float* __restrict__ W1,
               float* __restrict__ xpart) {
    __shared__ float hsum[HID];        // 8 KB
    __shared__ float cpart[16][AD];    // 2 KB
    int t  = threadIdx.x;              // 0..511
    int sc = blockIdx.x;               // 0..63
    int b  = blockIdx.y;               // 0..7

    const float* base = hs + ((size_t)b * S_LEN + (size_t)sc * S_PER) * HID;
    const f4* p = (const f4*)(base + t * 4);     // cols [t*4 .. t*4+3]
    f4 acc = (f4)(0.f);
#pragma unroll 8
    for (int s = 0; s < S_PER; ++s)
        acc += __builtin_nontemporal_load(p + (size_t)s * (HID / 4));
    *(f4*)&hsum[t * 4] = acc;
    __syncthreads();

    // c[j] = sum_h hsum[h]*W1[h][j]; 16 groups of 32 lanes, group g owns
    // h in [g*128, g*128+128). W1 reads 128B-coalesced per group, L2-hot.
    int j = t & 31, g = t >> 5;
    const float* w = W1 + (size_t)(g * 128) * AD + j;
    float c = 0.f;
#pragma unroll 4
    for (int k = 0; k < 128; ++k)
        c += hsum[g * 128 + k] * w[(size_t)k * AD];
    cpart[g][j] = c;
    __syncthreads();

    if (t < AD) {
        float s = 0.f;
#pragma unroll
        for (int gg = 0; gg < 16; ++gg) s += cpart[gg][t];
        xpart[((size_t)(b * SC + sc)) * AD + t] = s;
    }
}

// ---- Kernel 2: per-block controller redo + masked scale + Hadamard ----
// grid 256, block 128 -> one row per thread, 128 rows per block, 32 blocks
// per batch. Every block redundantly recomputes the tiny controller for its
// batch from xpart (8 KB, L2-hot) -> deterministic identical mask; then
// streams its 128 rows of rank_activations through the masked FWHT-16.
__global__ void ctrl_hadamard(const float* __restrict__ xpart,
                              const float* __restrict__ b1,
                              const float* __restrict__ gamma,
                              const float* __restrict__ beta,
                              const float* __restrict__ W2,
                              const float* __restrict__ b2v,
                              const float* __restrict__ mlog,
                              const float* __restrict__ rsc,
                              const float* __restrict__ ra,
                              float* __restrict__ out) {
    __shared__ float xp[4][AD];
    __shared__ float xv[AD];
    __shared__ float xg[AD];
    __shared__ float comb[R];
    __shared__ float ms[R];
    int t   = threadIdx.x;            // 0..127
    int blk = blockIdx.x;             // 0..255
    int b   = blk >> 5;               // 32 blocks per batch

    // --- controller (redundant per block, identical across a batch) ---
    int j = t & 31, g = t >> 5;       // 4 groups of 32
    const float* xb = xpart + (size_t)b * SC * AD;
    float s = 0.f;
#pragma unroll 8
    for (int r = 0; r < SC / 4; ++r)          // 16 rows per group
        s += xb[(size_t)(g * (SC / 4) + r) * AD + j];
    xp[g][j] = s;
    __syncthreads();

    if (t < AD) {
        float x = 0.f;
#pragma unroll
        for (int gg = 0; gg < 4; ++gg) x += xp[gg][t];
        xv[t] = x * (1.0f / (float)S_LEN) + b1[t];
    }
    __syncthreads();

    if (t < AD) {
        float mu = 0.f;
#pragma unroll
        for (int k = 0; k < AD; ++k) mu += xv[k];
        mu *= (1.0f / AD);
        float var = 0.f;
#pragma unroll
        for (int k = 0; k < AD; ++k) { float d = xv[k] - mu; var += d * d; }
        var *= (1.0f / AD);
        float x = (xv[t] - mu) * rsqrtf(var + 1e-5f) * gamma[t] + beta[t];
        xg[t] = 0.5f * x * (1.0f + erff(x * 0.70710678118654752f));  // exact GELU
    }
    __syncthreads();

    if (t < R) {
        float lg = b2v[t];
#pragma unroll
        for (int k = 0; k < AD; ++k) lg += xg[k] * W2[(size_t)k * R + t];
        comb[t] = lg + mlog[t];
    }
    __syncthreads();

    if (t < R) {
        float v = comb[t];
        int cnt = 0;
#pragma unroll
        for (int k = 0; k < R; ++k)
            cnt += (comb[k] > v) || (comb[k] == v && k < t);
        ms[t] = (cnt < 8) ? rsc[t] : 0.f;
    }
    __syncthreads();

    // --- masked scale + FWHT-16 (one row per thread) ---
    size_t row = (size_t)blk * 128 + t;
    const f4* src = (const f4*)(ra + row * R);
    float a[R];
#pragma unroll
    for (int i = 0; i < 4; ++i) {
        f4 v = __builtin_nontemporal_load(src + i);
        a[4 * i + 0] = v.x; a[4 * i + 1] = v.y;
        a[4 * i + 2] = v.z; a[4 * i + 3] = v.w;
    }
#pragma unroll
    for (int r = 0; r < R; ++r) a[r] *= ms[r];

    // FWHT-16 (Sylvester ordering); recursive /sqrt(n) => total 1/32
#pragma unroll
    for (int hstep = 1; hstep < R; hstep <<= 1) {
#pragma unroll
        for (int i = 0; i < R; ++i) {
            if ((i & hstep) == 0) {
                float u = a[i], v = a[i | hstep];
                a[i] = u + v; a[i | hstep] = u - v;
            }
        }
    }

    f4* dst = (f4*)(out + row * R);
#pragma unroll
    for (int i = 0; i < 4; ++i) {
        f4 v;
        v.x = a[4 * i + 0] * 0.03125f; v.y = a[4 * i + 1] * 0.03125f;
        v.z = a[4 * i + 2] * 0.03125f; v.w = a[4 * i + 3] * 0.03125f;
        __builtin_nontemporal_store(v, dst + i);
    }
}

extern "C" void kernel_launch(void* const* d_in, const int* in_sizes, int n_in,
                              void* d_out, int out_size, void* d_ws, size_t ws_size,
                              hipStream_t stream) {
    const float* hs    = (const float*)d_in[0];  // (8,4096,2048)
    const float* ra    = (const float*)d_in[1];  // (8,4096,16)
    const float* W1    = (const float*)d_in[2];  // (2048,32)
    const float* b1    = (const float*)d_in[3];  // (32)
    const float* gamma = (const float*)d_in[4];  // (32)
    const float* beta  = (const float*)d_in[5];  // (32)
    const float* W2    = (const float*)d_in[6];  // (32,16)
    const float* b2v   = (const float*)d_in[7];  // (16)
    const float* mlog  = (const float*)d_in[8];  // (16)
    const float* rsc   = (const float*)d_in[9];  // (16)
    float* out = (float*)d_out;

    float* xpart = (float*)d_ws;                 // 512*32 f32 = 64 KB

    pool_proj    <<<dim3(SC, NB), 512, 0, stream>>>(hs, W1, xpart);
    ctrl_hadamard<<<256, 128, 0, stream>>>(xpart, b1, gamma, beta,
                                           W2, b2v, mlog, rsc, ra, out);
}